// Round 2
// baseline (8629.443 us; speedup 1.0000x reference)
//
#include <hip/hip_runtime.h>

// ---------------------------------------------------------------------------
// GRU (2-layer, B=64, T=1024, I=256, H=512) + FC(512->256). FP32 I/O,
// bf16 MFMA internally. Persistent cooperative kernel, 256 WGs x 256 thr.
// R6 changes vs R5 (21124 us):
//  1. Layer-partitioned WGs: each WG owns 32 columns of ONE layer, skipping
//     the k-regions where its B is all-zero. Per-wave frags: 20 -> 16 (L1) /
//     12 (L0). Per-step sc1 A-traffic 20.5 MB -> 14.3 MB.
//  2. FC removed from the persistent loop: epilogue writes h1(t) to a 64 MB
//     __device__ bf16 history with normal cached stores; a separate GEMM
//     kernel (fc_out) computes out = hist @ Wfc^T + bfc afterwards.
//  3. Per-batch-half independent barriers (halves share no data): 16 arrivals
//     per group counter instead of 32; phase-0 init made half-local.
//  4. x(t+2) staging spread over 8 WGs per half (2 st32/thread).
// (Resubmitted unchanged in R1: GPU acquisition timed out both prior rounds;
//  no counters exist yet for this design.)
// ---------------------------------------------------------------------------

typedef __bf16 bf16x8 __attribute__((ext_vector_type(8)));
typedef float f32x16 __attribute__((ext_vector_type(16)));

// S ping-pong buffers: [2][64 b][1280 k] bf16 (fully rewritten every launch)
__device__ __align__(16) unsigned short g_S[2 * 64 * 1280];
// h1 history for the FC pass: [T*B][512] bf16 = 64 MB (normal cached stores)
__device__ __align__(16) unsigned short g_h1[1024 * 64 * 512];

__device__ __forceinline__ unsigned short f2b(float f) {
    unsigned u = __float_as_uint(f);
    u += 0x7fffu + ((u >> 16) & 1u);          // round to nearest even
    return (unsigned short)(u >> 16);
}
__device__ __forceinline__ unsigned int pack2(float a, float b) {
    return (unsigned)f2b(a) | ((unsigned)f2b(b) << 16);
}
// Agent-scope (cross-XCD coherent, L3) relaxed accessors
__device__ __forceinline__ void st32(void* p, unsigned int v) {
    __hip_atomic_store((unsigned int*)p, v, __ATOMIC_RELAXED, __HIP_MEMORY_SCOPE_AGENT);
}
__device__ __forceinline__ unsigned long long ld64(const void* p) {
    return __hip_atomic_load((const unsigned long long*)p, __ATOMIC_RELAXED,
                             __HIP_MEMORY_SCOPE_AGENT);
}
__device__ __forceinline__ bf16x8 ldfrag(const unsigned short* p) {   // 16B, L3-coherent
    union { unsigned long long q[2]; bf16x8 b; } cv;
    cv.q[0] = ld64(p);
    cv.q[1] = ld64(p + 4);
    return cv.b;
}
__device__ __forceinline__ float fsig(float x)  { return 1.0f / (1.0f + __expf(-x)); }
__device__ __forceinline__ float ftanh(float x) { return 1.0f - 2.0f / (__expf(2.0f * x) + 1.0f); }

__global__ __launch_bounds__(256, 1)
void gru_fused(const float* __restrict__ xin,   // [64][1024][256] fp32
               const float* __restrict__ Wih0, const float* __restrict__ bih0,
               const float* __restrict__ Whh0, const float* __restrict__ bhh0,
               const float* __restrict__ Wih1, const float* __restrict__ bih1,
               const float* __restrict__ Whh1, const float* __restrict__ bhh1,
               const float* __restrict__ Wfc,  const float* __restrict__ bfc,
               float* __restrict__ out, unsigned int* __restrict__ bar)
{
    __shared__ float ldsC[4224];          // [4 waves][32 rows][33] (pad: conflict-free)

    const int th = threadIdx.x;
    const int wg = blockIdx.x;            // 256 WGs (cooperative: co-resident)
    const int bh = wg >> 7;               // batch half
    const int r_ = wg & 127;
    const int lay = r_ >> 6;              // 0 = layer 1, 1 = layer 0
    const int cg  = r_ & 63;              // column group: units 8cg..8cg+7 of this layer
    const int v  = th >> 6;               // wave = K-split
    const int ln = th & 63;
    const int bloc = bh * 32;

    unsigned short* Sbuf0 = g_S;                  // [64 b][1280 k] bf16
    unsigned short* Sbuf1 = g_S + 64 * 1280;
    unsigned short* Sbuf[2] = {Sbuf0, Sbuf1};

    // per-half barrier state: 8 group counters (128 B apart) + 1 master
    unsigned int* grp    = bar + bh * 256;        // 8 x 32-u32 stride
    unsigned int* master = bar + 512 + bh * 32;

    unsigned int gen = 0;
    auto gridbar = [&]() {
        __syncthreads();                  // drains vmcnt(0): sc1 stores at L3
        gen++;
        if (th == 0) {
            unsigned old = __hip_atomic_fetch_add(&grp[(r_ & 7) * 32], 1u,
                              __ATOMIC_RELAXED, __HIP_MEMORY_SCOPE_AGENT);
            if ((old & 15u) == 15u)       // 16th arrival of this group this gen
                __hip_atomic_fetch_add(master, 1u,
                              __ATOMIC_RELAXED, __HIP_MEMORY_SCOPE_AGENT);
            while (__hip_atomic_load(master, __ATOMIC_RELAXED,
                                     __HIP_MEMORY_SCOPE_AGENT) < gen * 8u)
                __builtin_amdgcn_s_sleep(1);
        }
        __syncthreads();
    };

    // ------------------------------------------------------------------ phase 0
    // zero h-regions (k<1024) of both S buffers — HALF-LOCAL (per-half barrier!)
    {   // per half: 2 bufs x 32 rows x 512 u32 = 32768 = one per thread
        int ltid = (r_ << 8) | th;                 // [0, 32768)
        int buf = ltid >> 14, rem = ltid & 16383;
        int b = bloc + (rem >> 9), kp = rem & 511;
        st32(Sbuf[buf] + b * 1280 + kp * 2, 0u);
        // x(0) -> S0 x-region of this half: 32 b x 128 u32 = 4096
        if (ltid < 4096) {
            int bb = bloc + (ltid >> 7), i = (ltid & 127) * 2;
            const float* s = xin + (bb * 1024 + 0) * 256 + i;
            st32(Sbuf0 + bb * 1280 + 1024 + i, pack2(s[0], s[1]));
        }
    }

    // ------------------------- preload B-fragments from GLOBAL (fp32 -> bf16)
    // column n = (lay block) cg*32 + nl; nl = ty*8 + p (ty: 0=r,1=z,2=n_x,3=n_h;
    // p = unit within group). Layer 1 (lay=0): k-logical = k-phys in [0,1024)
    // (h0 then h1). Layer 0 (lay=1): k-logical in [0,768): [0,512)=h0 (hidden),
    // [512,768)=x; k-phys maps x to S region [1024,1280).
    bf16x8 breg[16];
    {
        const int nl = ln & 31, ty = nl >> 3, p = nl & 7;
        const int u = cg * 8 + p;
        const int kh = (ln >> 5) << 3;
        if (lay == 0) {                        // layer 1: 16 frags, K=1024
            #pragma unroll
            for (int ks = 0; ks < 16; ++ks) {
                const int k = v * 256 + ks * 16 + kh;
                const float* src = nullptr;
                if (k < 512) {                 // input = h0 -> Wih1
                    if (ty != 3) src = Wih1 + (u + (ty == 1 ? 512 : (ty == 2 ? 1024 : 0))) * 512 + k;
                } else {                       // hidden = h1 -> Whh1
                    if (ty != 2) src = Whh1 + (u + (ty == 1 ? 512 : (ty == 3 ? 1024 : 0))) * 512 + (k - 512);
                }
                bf16x8 z;
                #pragma unroll
                for (int j = 0; j < 8; ++j) z[j] = (__bf16)0.0f;
                if (src) {
                    #pragma unroll
                    for (int j = 0; j < 8; ++j) z[j] = (__bf16)src[j];
                }
                breg[ks] = z;
            }
        } else {                               // layer 0: 12 frags, K=768
            #pragma unroll
            for (int ks = 0; ks < 12; ++ks) {
                const int k = v * 192 + ks * 16 + kh;
                const float* src = nullptr;
                if (k < 512) {                 // hidden = h0 -> Whh0
                    if (ty != 2) src = Whh0 + (u + (ty == 1 ? 512 : (ty == 3 ? 1024 : 0))) * 512 + k;
                } else {                       // input = x -> Wih0
                    if (ty != 3) src = Wih0 + (u + (ty == 1 ? 512 : (ty == 2 ? 1024 : 0))) * 256 + (k - 512);
                }
                bf16x8 z;
                #pragma unroll
                for (int j = 0; j < 8; ++j) z[j] = (__bf16)0.0f;
                if (src) {
                    #pragma unroll
                    for (int j = 0; j < 8; ++j) z[j] = (__bf16)src[j];
                }
                breg[ks] = z;
            }
        }
    }

    // -------------------- epilogue roles: 128 threads x 2 adjacent units each
    const int ebl = th & 31;              // batch lane (row within half)
    const int eq  = (th >> 5) & 3;        // unit-pair index (units 2eq, 2eq+1 of the 8)
    const int u0 = cg * 8 + 2 * eq;
    const int eb = bloc + ebl;
    float ebs[2][4];
    {
        const float* bi  = lay ? bih0 : bih1;
        const float* bhp = lay ? bhh0 : bhh1;
        #pragma unroll
        for (int s = 0; s < 2; ++s) {
            int u = u0 + s;
            ebs[s][0] = bi[u]        + bhp[u];
            ebs[s][1] = bi[512 + u]  + bhp[512 + u];
            ebs[s][2] = bi[1024 + u];
            ebs[s][3] = bhp[1024 + u];
        }
    }
    float hprev[2][2] = {{0.f, 0.f}, {0.f, 0.f}};   // [unit][parity] fp32 state

    gridbar();   // phase-0 S buffers visible half-wide

    // ------------------------------------------------------------- time loop
    for (int t = -1; t < 1024; ++t) {
        const unsigned short* Sc = Sbuf[(t + 1) & 1];
        unsigned short* Sn       = Sbuf[t & 1];

        // GEMM: wave v covers its layer's K-slice (L1: 256 k, L0: 192 k)
        f32x16 acc;
        #pragma unroll
        for (int i = 0; i < 16; ++i) acc[i] = 0.0f;
        {
            const int m = ln & 31;
            const int kh = (ln >> 5) << 3;
            const unsigned short* arow = Sc + (bloc + m) * 1280 + kh;
            if (lay == 0) {
                const int kb = v * 256;
                #pragma unroll
                for (int ks = 0; ks < 16; ++ks) {
                    bf16x8 af = ldfrag(arow + kb + ks * 16);
                    acc = __builtin_amdgcn_mfma_f32_32x32x16_bf16(af, breg[ks], acc, 0, 0, 0);
                }
            } else {
                const int kb = v * 192;
                #pragma unroll
                for (int ks = 0; ks < 12; ++ks) {
                    const int klog = kb + ks * 16;
                    const int kp = (klog < 512) ? klog : klog + 512;   // x -> S[1024..)
                    bf16x8 af = ldfrag(arow + kp);
                    acc = __builtin_amdgcn_mfma_f32_32x32x16_bf16(af, breg[ks], acc, 0, 0, 0);
                }
            }
        }
        {   // partials -> LDS  (C: col=lane&31, row=(r&3)+8*(r>>2)+4*(lane>>5))
            const int col = ln & 31, rbase = (ln >> 5) << 2;
            #pragma unroll
            for (int r = 0; r < 16; ++r) {
                int row = (r & 3) + ((r >> 2) << 3) + rbase;
                ldsC[(v * 32 + row) * 33 + col] = acc[r];
            }
        }
        __syncthreads();

        if (th < 128) {   // fused gate epilogue: 2 units per thread, one layer
            float d[2][4];
            #pragma unroll
            for (int s = 0; s < 2; ++s)
                #pragma unroll
                for (int g = 0; g < 4; ++g) d[s][g] = 0.0f;
            #pragma unroll
            for (int w = 0; w < 4; ++w) {
                const float* Cw = ldsC + (w * 32 + ebl) * 33 + 2 * eq;
                #pragma unroll
                for (int s = 0; s < 2; ++s)
                    #pragma unroll
                    for (int g = 0; g < 4; ++g)
                        d[s][g] += Cw[g * 8 + s];
            }
            float hn[2];
            #pragma unroll
            for (int s = 0; s < 2; ++s) {
                float rg = fsig(d[s][0] + ebs[s][0]);
                float zg = fsig(d[s][1] + ebs[s][1]);
                float ng = ftanh((d[s][2] + ebs[s][2]) + rg * (d[s][3] + ebs[s][3]));
                float hold = hprev[s][(t + 1) & 1];
                hn[s] = ng + zg * (hold - ng);
            }
            if (lay == 1) {                        // layer 0 -> h0(t+1)
                hprev[0][t & 1] = hn[0]; hprev[1][t & 1] = hn[1];
                st32(Sn + eb * 1280 + u0, pack2(hn[0], hn[1]));
            } else if (t >= 0) {                   // layer 1 -> h1(t)
                hprev[0][t & 1] = hn[0]; hprev[1][t & 1] = hn[1];
                unsigned pk = pack2(hn[0], hn[1]);
                st32(Sn + eb * 1280 + 512 + u0, pk);
                // h1 history (normal cached store; flushed at kernel end)
                *(unsigned int*)(g_h1 + ((unsigned)t * 64 + eb) * 512 + u0) = pk;
            }
        }
        // x(t+2) -> S_next x-region: 8 layer-0 WGs per half, 4 rows each
        if (lay == 1 && cg < 8 && (t + 2) < 1024) {
            const int b = bloc + cg * 4 + (th >> 6);
            const int ic = (th & 63) * 4;
            const float* src = xin + (b * 1024 + (t + 2)) * 256 + ic;
            unsigned short* dst = Sn + b * 1280 + 1024 + ic;
            st32(dst,     pack2(src[0], src[1]));
            st32(dst + 2, pack2(src[2], src[3]));
        }

        gridbar();
    }
}

// ---------------------------------------------------------------------------
// FC pass: out[65536][256] = g_h1[65536][512] @ Wfc^T + bfc.
// 256 WGs x 4 waves = 1024 waves; wave w: n-tile = w&7 (32 cols), strides over
// 16 m-tiles of 32 rows. B (Wfc) cast fp32->bf16 into 32 register frags once.
// ---------------------------------------------------------------------------
__global__ __launch_bounds__(256, 1)
void fc_out(const float* __restrict__ Wfc, const float* __restrict__ bfc,
            float* __restrict__ out)
{
    const int th = threadIdx.x;
    const int ln = th & 63;
    const int v  = th >> 6;
    const int w  = blockIdx.x * 4 + v;    // [0, 1024)
    const int ntile = w & 7;
    const int mbase = w >> 3;             // [0, 128)
    const int kh = (ln >> 5) << 3;
    const int col = ln & 31;

    bf16x8 fb[32];
    {
        const int n = ntile * 32 + col;
        #pragma unroll
        for (int ks = 0; ks < 32; ++ks) {
            const float* s = Wfc + n * 512 + ks * 16 + kh;
            bf16x8 z;
            #pragma unroll
            for (int j = 0; j < 8; ++j) z[j] = (__bf16)s[j];
            fb[ks] = z;
        }
    }
    const float bias = bfc[ntile * 32 + col];

    for (int i = 0; i < 16; ++i) {
        const int mt = mbase + i * 128;   // m-tile [0, 2048)
        const unsigned short* ar = g_h1 + ((unsigned)(mt * 32 + col)) * 512 + kh;
        f32x16 acc;
        #pragma unroll
        for (int q = 0; q < 16; ++q) acc[q] = 0.0f;
        #pragma unroll
        for (int ks = 0; ks < 32; ++ks) {
            bf16x8 af = *(const bf16x8*)(ar + ks * 16);
            acc = __builtin_amdgcn_mfma_f32_32x32x16_bf16(af, fb[ks], acc, 0, 0, 0);
        }
        const int rb = (ln >> 5) << 2;
        #pragma unroll
        for (int r = 0; r < 16; ++r) {
            int row = (r & 3) + ((r >> 2) << 3) + rb;
            out[((unsigned)(mt * 32 + row)) * 256 + ntile * 32 + col] = acc[r] + bias;
        }
    }
}

extern "C" void kernel_launch(void* const* d_in, const int* in_sizes, int n_in,
                              void* d_out, int out_size, void* d_ws, size_t ws_size,
                              hipStream_t stream) {
    (void)in_sizes; (void)n_in; (void)out_size; (void)ws_size;
    hipMemsetAsync(d_ws, 0, 4096, stream);   // barrier counters (monotonic per launch)
    const float* xin  = (const float*)d_in[0];
    const float* Wih0 = (const float*)d_in[1];
    const float* bih0 = (const float*)d_in[2];
    const float* Whh0 = (const float*)d_in[3];
    const float* bhh0 = (const float*)d_in[4];
    const float* Wih1 = (const float*)d_in[5];
    const float* bih1 = (const float*)d_in[6];
    const float* Whh1 = (const float*)d_in[7];
    const float* bhh1 = (const float*)d_in[8];
    const float* Wfc  = (const float*)d_in[9];
    const float* bfc  = (const float*)d_in[10];
    float* outp = (float*)d_out;
    unsigned int* barp = (unsigned int*)d_ws;
    void* args[] = {&xin, &Wih0, &bih0, &Whh0, &bhh0, &Wih1, &bih1,
                    &Whh1, &bhh1, &Wfc, &bfc, &outp, &barp};
    hipLaunchCooperativeKernel((void*)gru_fused, dim3(256), dim3(256),
                               args, 0, stream);
    hipLaunchKernelGGL(fc_out, dim3(256), dim3(256), 0, stream,
                       Wfc, bfc, outp);
}